// Round 3
// baseline (267.874 us; speedup 1.0000x reference)
//
#include <hip/hip_runtime.h>

// Problem: B=128, N=65536, h=30.
// loss = sum_b sum_i ||gt[b] - (cand[b,i]+off[b,i])||^2  (argsort is a full
// permutation summed over afterwards -> irrelevant). RCNN passthrough.
// Output: RCNN_cls_result flat (B*N*2 floats) ++ loss (1 float).
//
// R1 lesson: same-address atomics serialize -> block partials.
// R2 lesson: bounds-checked per-iter loop -> 1.9 TB/s.
// R3 lesson: __builtin_nontemporal_store needs a clang ext_vector type.
// R4 lesson: sched_barrier(0) can't stop IR-level load sinking (VGPR stayed 32).
// R5 lesson: R2 bench was a STALE BINARY (VGPR/SGPR/FETCH bit-identical to R1;
//   48 live asm-output VGPRs cannot fit in 32) -> inline-asm ILP never tested.
//   Re-derived Little's law: 20 waves x 1KB in flight >> 9KB needed for full
//   BW. ILP was never the lever. This round: restructure to the PROVEN 6.3
//   TB/s pattern (m13 grid-stride copy) + algebraic loss split
//     sum||g-p||^2 = sum||p||^2 - 2 sum_b g_b . S1_b + N * sum_b ||g_b||^2
//   so the hot kernels are pure streams (no y read, no preamble, no shuffles
//   until the tail). Three dispatches; the pure-copy dispatch's hbm_gbps is
//   the diagnostic: if IT also runs at 2 TB/s the cap is systemic, not
//   structural. Kernel renames double as staleness detectors.

typedef float v4f __attribute__((ext_vector_type(4)));

// ---------------------------------------------------------------- pure copy
__global__ __launch_bounds__(256) void rcnn_copy_kernel(
    const v4f* __restrict__ rcnn, v4f* __restrict__ out, int n4)
{
    const int stride = gridDim.x * 256;
    for (int i = blockIdx.x * 256 + threadIdx.x; i < n4; i += stride)
        __builtin_nontemporal_store(rcnn[i], &out[i]);
}

// ------------------------------------------------- loss partials (2 streams)
// Each block owns a contiguous chunk that lies inside ONE sample row b
// (chunk divides row4), so (s2, s1x, s1y) bind to a single b.
__global__ __launch_bounds__(256) void loss_partials_kernel(
    const v4f* __restrict__ cand, const v4f* __restrict__ off,
    float* __restrict__ partials,   // [3 * nblk] SoA: s2 | s1x | s1y
    int chunk, int nblk)
{
    const int base = blockIdx.x * chunk;
    float s2 = 0.f, s1x = 0.f, s1y = 0.f;
    for (int i = base + threadIdx.x; i < base + chunk; i += 256) {
        v4f c = cand[i], o = off[i];
        float px0 = c.x + o.x, py0 = c.y + o.y;
        float px1 = c.z + o.z, py1 = c.w + o.w;
        s2  += px0 * px0; s2 += py0 * py0;
        s2  += px1 * px1; s2 += py1 * py1;
        s1x += px0 + px1;
        s1y += py0 + py1;
    }
    #pragma unroll
    for (int s = 32; s > 0; s >>= 1) {
        s2  += __shfl_down(s2,  s, 64);
        s1x += __shfl_down(s1x, s, 64);
        s1y += __shfl_down(s1y, s, 64);
    }
    __shared__ float lds[12];
    int lane = threadIdx.x & 63, wid = threadIdx.x >> 6;
    if (lane == 0) { lds[wid] = s2; lds[4 + wid] = s1x; lds[8 + wid] = s1y; }
    __syncthreads();
    if (threadIdx.x == 0) {
        partials[blockIdx.x]            = lds[0] + lds[1] + lds[2]  + lds[3];
        partials[nblk + blockIdx.x]     = lds[4] + lds[5] + lds[6]  + lds[7];
        partials[2 * nblk + blockIdx.x] = lds[8] + lds[9] + lds[10] + lds[11];
    }
}

// ------------------------------------------------------------- final reduce
__global__ __launch_bounds__(256) void final_reduce_gt_kernel(
    const float* __restrict__ partials, const float* __restrict__ y,
    float* __restrict__ loss_slot,
    int nblk, int B, int h, int row4, int chunk)
{
    extern __shared__ float dyn[];          // [B*h*2] y staging ++ [2*B] gt
    float* yld = dyn;
    float* gt  = dyn + B * h * 2;

    const int ytot = B * h * 2;
    for (int i = threadIdx.x; i < ytot; i += 256) yld[i] = y[i];
    __syncthreads();

    for (int b = threadIdx.x; b < B; b += 256) {
        float gx = 0.f, gy = 0.f;
        const float* yr = yld + (size_t)b * h * 2;
        for (int i = 0; i < h; ++i) { gx += yr[2 * i]; gy += yr[2 * i + 1]; }
        gt[2 * b] = gx; gt[2 * b + 1] = gy;
    }
    __syncthreads();

    const int blocks_per_b = row4 / chunk;
    const float cnt_b = (float)(row4 * 2);   // points per sample = N
    float acc = 0.f;
    for (int k = threadIdx.x; k < nblk; k += 256) {
        int b = k / blocks_per_b;
        float gx = gt[2 * b], gy = gt[2 * b + 1];
        acc += partials[k]
             - 2.f * (gx * partials[nblk + k] + gy * partials[2 * nblk + k]);
    }
    for (int b = threadIdx.x; b < B; b += 256) {
        float gx = gt[2 * b], gy = gt[2 * b + 1];
        acc += cnt_b * (gx * gx + gy * gy);
    }

    #pragma unroll
    for (int s = 32; s > 0; s >>= 1) acc += __shfl_down(acc, s, 64);
    __shared__ float red[4];
    int lane = threadIdx.x & 63, wid = threadIdx.x >> 6;
    if (lane == 0) red[wid] = acc;
    __syncthreads();
    if (threadIdx.x == 0)
        *loss_slot = red[0] + red[1] + red[2] + red[3];
}

extern "C" void kernel_launch(void* const* d_in, const int* in_sizes, int n_in,
                              void* d_out, int out_size, void* d_ws, size_t ws_size,
                              hipStream_t stream) {
    const float* candidate = (const float*)d_in[2];
    const float* rcnn      = (const float*)d_in[3];
    const float* offset    = (const float*)d_in[4];
    const float* y         = (const float*)d_in[6];

    const int B = in_sizes[8];                 // horizon is [B]
    const int N = in_sizes[3] / (B * 2);       // RCNN is [B,N,2]
    const int h = in_sizes[6] / (B * 2);       // y is [B*h,2]

    float* out_f     = (float*)d_out;
    float* loss_slot = out_f + (size_t)B * N * 2;   // last element of d_out
    float* partials  = (float*)d_ws;

    const int n4   = (B * N * 2) / 4;          // 4,194,304 float4s
    const int row4 = N / 2;                    // 32,768 float4s per sample row
    int chunk = 2048;                          // divides row4 for N=64K
    while (row4 % chunk) chunk >>= 1;          // safety for other shapes
    const int nblk = n4 / chunk;               // 2048 blocks

    loss_partials_kernel<<<nblk, 256, 0, stream>>>(
        (const v4f*)candidate, (const v4f*)offset, partials, chunk, nblk);

    rcnn_copy_kernel<<<2048, 256, 0, stream>>>(
        (const v4f*)rcnn, (v4f*)d_out, n4);

    const size_t shmem = (size_t)(B * h * 2 + 2 * B) * sizeof(float);
    final_reduce_gt_kernel<<<1, 256, shmem, stream>>>(
        partials, y, loss_slot, nblk, B, h, row4, chunk);
}

// Round 4
// 267.155 us; speedup vs baseline: 1.0027x; 1.0027x over previous
//
#include <hip/hip_runtime.h>

// Problem: B=128, N=65536, h=30.
// loss = sum_b sum_i ||gt[b] - (cand[b,i]+off[b,i])||^2  (argsort is a full
// permutation summed over afterwards -> irrelevant). RCNN passthrough.
// Output: RCNN_cls_result flat (B*N*2 floats) ++ loss (1 float).
//
// R1 lesson: same-address atomics serialize -> block partials (NOT one slot).
// R2 lesson: bounds-checked per-iter loop -> 1.9 TB/s.
// R3 lesson: __builtin_nontemporal_store needs a clang ext_vector type.
// R4 lesson: sched_barrier(0) can't stop IR-level load sinking.
// R5 lesson: stale-binary bench; also Little's law says concurrency was never
//   the limiter (20 waves/CU x 1KB >> needed). ILP was a dead end.
// R6 lesson (split experiment): pure 2-stream read = 2.66 TB/s effective;
//   fused R0 = 3.05; implied pure copy ~3.0. Cap is ~3 TB/s effective and
//   STRUCTURE-INDEPENDENT (implied queueing latency ~4500cy = saturated
//   service, not insufficient outstanding loads). Fusion wins because read
//   and write streams overlap under the same cap; the split also paid an
//   extra dispatch. This round: re-fuse to ONE 256MiB-traffic kernel, keep
//   the algebraic loss split (no y read / no gt preamble / no per-point gt
//   chain):  sum||g-p||^2 = s2 - 2 g.s1 + N*||g||^2  per sample.
//   If this again pins at ~3 TB/s effective -> practical roofline reached.

typedef float v4f __attribute__((ext_vector_type(4)));

// One kernel carries ALL hot traffic: cand+off+rcnn reads, out write,
// s2/s1x/s1y partials. Each block owns a contiguous chunk inside ONE sample
// row (chunk divides row4), so partials bind to a single b.
__global__ __launch_bounds__(256) void fused_stream_kernel(
    const v4f* __restrict__ cand, const v4f* __restrict__ off,
    const v4f* __restrict__ rcnn, v4f* __restrict__ out,
    float* __restrict__ partials,   // [3 * nblk] SoA: s2 | s1x | s1y
    int chunk, int nblk)
{
    const int base = blockIdx.x * chunk;
    float s2 = 0.f, s1x = 0.f, s1y = 0.f;
    for (int i = base + threadIdx.x; i < base + chunk; i += 256) {
        v4f c = cand[i], o = off[i], r = rcnn[i];
        __builtin_nontemporal_store(r, &out[i]);
        float px0 = c.x + o.x, py0 = c.y + o.y;
        float px1 = c.z + o.z, py1 = c.w + o.w;
        s2  += px0 * px0; s2 += py0 * py0;
        s2  += px1 * px1; s2 += py1 * py1;
        s1x += px0 + px1;
        s1y += py0 + py1;
    }
    #pragma unroll
    for (int s = 32; s > 0; s >>= 1) {
        s2  += __shfl_down(s2,  s, 64);
        s1x += __shfl_down(s1x, s, 64);
        s1y += __shfl_down(s1y, s, 64);
    }
    __shared__ float lds[12];
    int lane = threadIdx.x & 63, wid = threadIdx.x >> 6;
    if (lane == 0) { lds[wid] = s2; lds[4 + wid] = s1x; lds[8 + wid] = s1y; }
    __syncthreads();
    if (threadIdx.x == 0) {
        partials[blockIdx.x]            = lds[0] + lds[1] + lds[2]  + lds[3];
        partials[nblk + blockIdx.x]     = lds[4] + lds[5] + lds[6]  + lds[7];
        partials[2 * nblk + blockIdx.x] = lds[8] + lds[9] + lds[10] + lds[11];
    }
}

// ------------------------------------------------------------- final reduce
__global__ __launch_bounds__(256) void final_reduce_gt_kernel(
    const float* __restrict__ partials, const float* __restrict__ y,
    float* __restrict__ loss_slot,
    int nblk, int B, int h, int row4, int chunk)
{
    extern __shared__ float dyn[];          // [B*h*2] y staging ++ [2*B] gt
    float* yld = dyn;
    float* gt  = dyn + B * h * 2;

    const int ytot = B * h * 2;
    for (int i = threadIdx.x; i < ytot; i += 256) yld[i] = y[i];
    __syncthreads();

    for (int b = threadIdx.x; b < B; b += 256) {
        float gx = 0.f, gy = 0.f;
        const float* yr = yld + (size_t)b * h * 2;
        for (int i = 0; i < h; ++i) { gx += yr[2 * i]; gy += yr[2 * i + 1]; }
        gt[2 * b] = gx; gt[2 * b + 1] = gy;
    }
    __syncthreads();

    const int blocks_per_b = row4 / chunk;
    const float cnt_b = (float)(row4 * 2);   // points per sample = N
    float acc = 0.f;
    for (int k = threadIdx.x; k < nblk; k += 256) {
        int b = k / blocks_per_b;
        float gx = gt[2 * b], gy = gt[2 * b + 1];
        acc += partials[k]
             - 2.f * (gx * partials[nblk + k] + gy * partials[2 * nblk + k]);
    }
    for (int b = threadIdx.x; b < B; b += 256) {
        float gx = gt[2 * b], gy = gt[2 * b + 1];
        acc += cnt_b * (gx * gx + gy * gy);
    }

    #pragma unroll
    for (int s = 32; s > 0; s >>= 1) acc += __shfl_down(acc, s, 64);
    __shared__ float red[4];
    int lane = threadIdx.x & 63, wid = threadIdx.x >> 6;
    if (lane == 0) red[wid] = acc;
    __syncthreads();
    if (threadIdx.x == 0)
        *loss_slot = red[0] + red[1] + red[2] + red[3];
}

extern "C" void kernel_launch(void* const* d_in, const int* in_sizes, int n_in,
                              void* d_out, int out_size, void* d_ws, size_t ws_size,
                              hipStream_t stream) {
    const float* candidate = (const float*)d_in[2];
    const float* rcnn      = (const float*)d_in[3];
    const float* offset    = (const float*)d_in[4];
    const float* y         = (const float*)d_in[6];

    const int B = in_sizes[8];                 // horizon is [B]
    const int N = in_sizes[3] / (B * 2);       // RCNN is [B,N,2]
    const int h = in_sizes[6] / (B * 2);       // y is [B*h,2]

    float* out_f     = (float*)d_out;
    float* loss_slot = out_f + (size_t)B * N * 2;   // last element of d_out
    float* partials  = (float*)d_ws;

    const int n4   = (B * N * 2) / 4;          // 4,194,304 float4s
    const int row4 = N / 2;                    // 32,768 float4s per sample row
    int chunk = 2048;                          // divides row4 for N=64K
    while (row4 % chunk) chunk >>= 1;          // safety for other shapes
    const int nblk = n4 / chunk;               // 2048 blocks, 8/CU exact

    fused_stream_kernel<<<nblk, 256, 0, stream>>>(
        (const v4f*)candidate, (const v4f*)offset, (const v4f*)rcnn,
        (v4f*)d_out, partials, chunk, nblk);

    const size_t shmem = (size_t)(B * h * 2 + 2 * B) * sizeof(float);
    final_reduce_gt_kernel<<<1, 256, shmem, stream>>>(
        partials, y, loss_slot, nblk, B, h, row4, chunk);
}

// Round 5
// 266.040 us; speedup vs baseline: 1.0069x; 1.0042x over previous
//
#include <hip/hip_runtime.h>

// Problem: B=128, N=65536, h=30.
// loss = sum_b sum_i ||gt[b] - (cand[b,i]+off[b,i])||^2  (argsort is a full
// permutation summed over afterwards -> irrelevant). RCNN passthrough.
// Output: RCNN_cls_result flat (B*N*2 floats) ++ loss (1 float).
//
// R1 lesson: same-address atomics serialize -> block partials (NOT one slot).
// R2 lesson: bounds-checked per-iter loop -> 1.9 TB/s.
// R3 lesson: __builtin_nontemporal_store needs a clang ext_vector type.
// R4 lesson: sched_barrier(0) can't stop IR-level load sinking.
// R5 lesson: stale-binary bench (VGPR fingerprint identical); ILP via inline
//   asm never actually tested; Little's law says wave-level concurrency was
//   never the limiter anyway.
// R6 lesson (split): pure 2-stream read 2.66 TB/s eff; fused ~3.0; implied
//   pure copy ~3.5-3.8. Wall is ~3 TB/s effective for this working set.
// R7 lesson (fused algebraic, 2048 blk, rolled loop): 89-93 us — REGRESSED vs
//   R1's 86. VGPR=16: rolled loop killed cross-iteration pipelining; grid
//   halved. Structure matters +-7%; R1 geometry (4096 blk, unrolled U=4,
//   upfront loads) is the measured optimum. This round: R1 geometry +
//   algebraic loss (no y read / no gt preamble / no butterfly in hot kernel):
//     sum||g-p||^2 = s2 - 2 g.s1 + N*||g||^2   per sample b.
//   Last untested cell of the {geometry x algebra} matrix. If < 2% vs R1 ->
//   declare practical roofline (pre-committed).
// Rejected: last-block final-reduce fold (d_ws has no guaranteed zero state;
//   the required counter memset dispatch costs what the reduce dispatch costs).

typedef float v4f __attribute__((ext_vector_type(4)));

// Each block owns a contiguous chunk of 1024 float4s lying inside ONE sample
// row (1024 divides row4=32768), so (s2,s1x,s1y) bind to a single b.
__global__ __launch_bounds__(256) void fused_r1geom_kernel(
    const v4f* __restrict__ cand, const v4f* __restrict__ off,
    const v4f* __restrict__ rcnn, v4f* __restrict__ out,
    float* __restrict__ partials,   // [3 * nblk] SoA: s2 | s1x | s1y
    int n4, int nblk)
{
    constexpr int U = 4;
    const size_t base = (size_t)blockIdx.x * (256 * U);

    float s2 = 0.f, s1x = 0.f, s1y = 0.f;
    if (base + 256 * U <= (size_t)n4) {      // uniform fast path (exact grid)
        // Issue all loads before any consumer (R1's measured-best pattern).
        v4f c[U], o[U], r[U];
        #pragma unroll
        for (int u = 0; u < U; ++u) c[u] = cand[base + u * 256 + threadIdx.x];
        #pragma unroll
        for (int u = 0; u < U; ++u) o[u] = off[base + u * 256 + threadIdx.x];
        #pragma unroll
        for (int u = 0; u < U; ++u) r[u] = rcnn[base + u * 256 + threadIdx.x];

        #pragma unroll
        for (int u = 0; u < U; ++u) {
            __builtin_nontemporal_store(r[u], &out[base + u * 256 + threadIdx.x]);
            float px0 = c[u].x + o[u].x, py0 = c[u].y + o[u].y;
            float px1 = c[u].z + o[u].z, py1 = c[u].w + o[u].w;
            s2  += px0 * px0; s2 += py0 * py0;
            s2  += px1 * px1; s2 += py1 * py1;
            s1x += px0 + px1;
            s1y += py0 + py1;
        }
    } else {                                  // tail (not taken for B=128,N=64K)
        #pragma unroll
        for (int u = 0; u < U; ++u) {
            size_t idx = base + u * 256 + threadIdx.x;
            if (idx < (size_t)n4) {
                v4f c = cand[idx], o = off[idx], r = rcnn[idx];
                __builtin_nontemporal_store(r, &out[idx]);
                float px0 = c.x + o.x, py0 = c.y + o.y;
                float px1 = c.z + o.z, py1 = c.w + o.w;
                s2  += px0 * px0; s2 += py0 * py0;
                s2  += px1 * px1; s2 += py1 * py1;
                s1x += px0 + px1;
                s1y += py0 + py1;
            }
        }
    }

    #pragma unroll
    for (int s = 32; s > 0; s >>= 1) {
        s2  += __shfl_down(s2,  s, 64);
        s1x += __shfl_down(s1x, s, 64);
        s1y += __shfl_down(s1y, s, 64);
    }
    __shared__ float lds[12];
    int lane = threadIdx.x & 63, wid = threadIdx.x >> 6;
    if (lane == 0) { lds[wid] = s2; lds[4 + wid] = s1x; lds[8 + wid] = s1y; }
    __syncthreads();
    if (threadIdx.x == 0) {
        partials[blockIdx.x]            = lds[0] + lds[1] + lds[2]  + lds[3];
        partials[nblk + blockIdx.x]     = lds[4] + lds[5] + lds[6]  + lds[7];
        partials[2 * nblk + blockIdx.x] = lds[8] + lds[9] + lds[10] + lds[11];
    }
}

// ------------------------------------------------------------- final reduce
__global__ __launch_bounds__(256) void final_reduce_gt_kernel(
    const float* __restrict__ partials, const float* __restrict__ y,
    float* __restrict__ loss_slot,
    int nblk, int B, int h, int row4, int chunk)
{
    extern __shared__ float dyn[];          // [B*h*2] y staging ++ [2*B] gt
    float* yld = dyn;
    float* gt  = dyn + B * h * 2;

    const int ytot = B * h * 2;
    for (int i = threadIdx.x; i < ytot; i += 256) yld[i] = y[i];
    __syncthreads();

    for (int b = threadIdx.x; b < B; b += 256) {
        float gx = 0.f, gy = 0.f;
        const float* yr = yld + (size_t)b * h * 2;
        for (int i = 0; i < h; ++i) { gx += yr[2 * i]; gy += yr[2 * i + 1]; }
        gt[2 * b] = gx; gt[2 * b + 1] = gy;
    }
    __syncthreads();

    const int blocks_per_b = row4 / chunk;
    const float cnt_b = (float)(row4 * 2);   // points per sample = N
    float acc = 0.f;
    for (int k = threadIdx.x; k < nblk; k += 256) {
        int b = k / blocks_per_b;
        float gx = gt[2 * b], gy = gt[2 * b + 1];
        acc += partials[k]
             - 2.f * (gx * partials[nblk + k] + gy * partials[2 * nblk + k]);
    }
    for (int b = threadIdx.x; b < B; b += 256) {
        float gx = gt[2 * b], gy = gt[2 * b + 1];
        acc += cnt_b * (gx * gx + gy * gy);
    }

    #pragma unroll
    for (int s = 32; s > 0; s >>= 1) acc += __shfl_down(acc, s, 64);
    __shared__ float red[4];
    int lane = threadIdx.x & 63, wid = threadIdx.x >> 6;
    if (lane == 0) red[wid] = acc;
    __syncthreads();
    if (threadIdx.x == 0)
        *loss_slot = red[0] + red[1] + red[2] + red[3];
}

extern "C" void kernel_launch(void* const* d_in, const int* in_sizes, int n_in,
                              void* d_out, int out_size, void* d_ws, size_t ws_size,
                              hipStream_t stream) {
    const float* candidate = (const float*)d_in[2];
    const float* rcnn      = (const float*)d_in[3];
    const float* offset    = (const float*)d_in[4];
    const float* y         = (const float*)d_in[6];

    const int B = in_sizes[8];                 // horizon is [B]
    const int N = in_sizes[3] / (B * 2);       // RCNN is [B,N,2]
    const int h = in_sizes[6] / (B * 2);       // y is [B*h,2]

    float* out_f     = (float*)d_out;
    float* loss_slot = out_f + (size_t)B * N * 2;   // last element of d_out
    float* partials  = (float*)d_ws;

    const int n4   = (B * N * 2) / 4;          // 4,194,304 float4s
    const int row4 = N / 2;                    // 32,768 float4s per sample row
    const int chunk = 256 * 4;                 // 1024 float4s, divides row4
    const int nblk  = (n4 + chunk - 1) / chunk;   // 4096, exact

    fused_r1geom_kernel<<<nblk, 256, 0, stream>>>(
        (const v4f*)candidate, (const v4f*)offset, (const v4f*)rcnn,
        (v4f*)d_out, partials, n4, nblk);

    const size_t shmem = (size_t)(B * h * 2 + 2 * B) * sizeof(float);
    final_reduce_gt_kernel<<<1, 256, shmem, stream>>>(
        partials, y, loss_slot, nblk, B, h, row4, chunk);
}

// Round 6
// 259.661 us; speedup vs baseline: 1.0316x; 1.0246x over previous
//
#include <hip/hip_runtime.h>

// Problem: B=128, N=65536, h=30.
// loss = sum_b sum_i ||gt[b] - (cand[b,i]+off[b,i])||^2  (argsort is a full
// permutation summed over afterwards -> irrelevant). RCNN passthrough.
// Output: RCNN_cls_result flat (B*N*2 floats) ++ loss (1 float).
//
// R1 lesson: same-address atomics serialize -> block partials (NOT one slot).
// R2 lesson: bounds-checked per-iter loop -> 1.9 TB/s.
// R3 lesson: __builtin_nontemporal_store needs a clang ext_vector type.
// R4 lesson: sched_barrier(0) can't stop IR-level load sinking.
// R5 lesson: stale-binary bench; wave-level concurrency was never the limiter.
// R6 lesson (split): pure 2-stream read 2.66 TB/s eff; fused ~3.0-3.2.
// R7 lesson (rolled 2048-blk): 89-93 us, regression; R1 geometry is optimal.
// R8 lesson (R1 geom + algebraic): 83.5 us median, 2.0 TB/s HBM — SAME wall
//   across 6 structures. New model: service is MSHR-occupancy-capped:
//   256 CU x ~64 line-slots x 128 B / ~900cy HBM latency = 2.3 TB/s — matches.
//   Concurrency can't help (explains structure-independence); lowering AVG
//   LATENCY can (slots recycle faster). This round, one variable: rcnn loads
//   become NONTEMPORAL so the 64 MiB rcnn stream stops thrashing L3, letting
//   cand+off (exactly 128 MiB vs 256 MiB L3) stay resident -> their loads
//   become ~all L3-hits at ~half latency -> ~2x slot turnover on 2/3 of reads.
//   Predict: FETCH 98.3 -> ~66-75 MB, main 84 -> 60-72 us. If within +-3% of
//   R5: mechanism space exhausted, PRE-COMMIT to <<ROOFLINE>> next round.

typedef float v4f __attribute__((ext_vector_type(4)));

// Each block owns a contiguous chunk of 1024 float4s lying inside ONE sample
// row (1024 divides row4=32768), so (s2,s1x,s1y) bind to a single b.
__global__ __launch_bounds__(256) void fused_ntsteer_kernel(
    const v4f* __restrict__ cand, const v4f* __restrict__ off,
    const v4f* __restrict__ rcnn, v4f* __restrict__ out,
    float* __restrict__ partials,   // [3 * nblk] SoA: s2 | s1x | s1y
    int n4, int nblk)
{
    constexpr int U = 4;
    const size_t base = (size_t)blockIdx.x * (256 * U);

    float s2 = 0.f, s1x = 0.f, s1y = 0.f;
    if (base + 256 * U <= (size_t)n4) {      // uniform fast path (exact grid)
        // Issue all loads before any consumer (R1's measured-best pattern).
        // cand/off: regular loads (allowed to allocate/stay in L3).
        // rcnn: NONTEMPORAL loads (streamed; do not thrash L3).
        v4f c[U], o[U], r[U];
        #pragma unroll
        for (int u = 0; u < U; ++u) c[u] = cand[base + u * 256 + threadIdx.x];
        #pragma unroll
        for (int u = 0; u < U; ++u) o[u] = off[base + u * 256 + threadIdx.x];
        #pragma unroll
        for (int u = 0; u < U; ++u)
            r[u] = __builtin_nontemporal_load(&rcnn[base + u * 256 + threadIdx.x]);

        #pragma unroll
        for (int u = 0; u < U; ++u) {
            __builtin_nontemporal_store(r[u], &out[base + u * 256 + threadIdx.x]);
            float px0 = c[u].x + o[u].x, py0 = c[u].y + o[u].y;
            float px1 = c[u].z + o[u].z, py1 = c[u].w + o[u].w;
            s2  += px0 * px0; s2 += py0 * py0;
            s2  += px1 * px1; s2 += py1 * py1;
            s1x += px0 + px1;
            s1y += py0 + py1;
        }
    } else {                                  // tail (not taken for B=128,N=64K)
        #pragma unroll
        for (int u = 0; u < U; ++u) {
            size_t idx = base + u * 256 + threadIdx.x;
            if (idx < (size_t)n4) {
                v4f c = cand[idx], o = off[idx];
                v4f r = __builtin_nontemporal_load(&rcnn[idx]);
                __builtin_nontemporal_store(r, &out[idx]);
                float px0 = c.x + o.x, py0 = c.y + o.y;
                float px1 = c.z + o.z, py1 = c.w + o.w;
                s2  += px0 * px0; s2 += py0 * py0;
                s2  += px1 * px1; s2 += py1 * py1;
                s1x += px0 + px1;
                s1y += py0 + py1;
            }
        }
    }

    #pragma unroll
    for (int s = 32; s > 0; s >>= 1) {
        s2  += __shfl_down(s2,  s, 64);
        s1x += __shfl_down(s1x, s, 64);
        s1y += __shfl_down(s1y, s, 64);
    }
    __shared__ float lds[12];
    int lane = threadIdx.x & 63, wid = threadIdx.x >> 6;
    if (lane == 0) { lds[wid] = s2; lds[4 + wid] = s1x; lds[8 + wid] = s1y; }
    __syncthreads();
    if (threadIdx.x == 0) {
        partials[blockIdx.x]            = lds[0] + lds[1] + lds[2]  + lds[3];
        partials[nblk + blockIdx.x]     = lds[4] + lds[5] + lds[6]  + lds[7];
        partials[2 * nblk + blockIdx.x] = lds[8] + lds[9] + lds[10] + lds[11];
    }
}

// ------------------------------------------------------------- final reduce
__global__ __launch_bounds__(256) void final_reduce_gt_kernel(
    const float* __restrict__ partials, const float* __restrict__ y,
    float* __restrict__ loss_slot,
    int nblk, int B, int h, int row4, int chunk)
{
    extern __shared__ float dyn[];          // [B*h*2] y staging ++ [2*B] gt
    float* yld = dyn;
    float* gt  = dyn + B * h * 2;

    const int ytot = B * h * 2;
    for (int i = threadIdx.x; i < ytot; i += 256) yld[i] = y[i];
    __syncthreads();

    for (int b = threadIdx.x; b < B; b += 256) {
        float gx = 0.f, gy = 0.f;
        const float* yr = yld + (size_t)b * h * 2;
        for (int i = 0; i < h; ++i) { gx += yr[2 * i]; gy += yr[2 * i + 1]; }
        gt[2 * b] = gx; gt[2 * b + 1] = gy;
    }
    __syncthreads();

    const int blocks_per_b = row4 / chunk;
    const float cnt_b = (float)(row4 * 2);   // points per sample = N
    float acc = 0.f;
    for (int k = threadIdx.x; k < nblk; k += 256) {
        int b = k / blocks_per_b;
        float gx = gt[2 * b], gy = gt[2 * b + 1];
        acc += partials[k]
             - 2.f * (gx * partials[nblk + k] + gy * partials[2 * nblk + k]);
    }
    for (int b = threadIdx.x; b < B; b += 256) {
        float gx = gt[2 * b], gy = gt[2 * b + 1];
        acc += cnt_b * (gx * gx + gy * gy);
    }

    #pragma unroll
    for (int s = 32; s > 0; s >>= 1) acc += __shfl_down(acc, s, 64);
    __shared__ float red[4];
    int lane = threadIdx.x & 63, wid = threadIdx.x >> 6;
    if (lane == 0) red[wid] = acc;
    __syncthreads();
    if (threadIdx.x == 0)
        *loss_slot = red[0] + red[1] + red[2] + red[3];
}

extern "C" void kernel_launch(void* const* d_in, const int* in_sizes, int n_in,
                              void* d_out, int out_size, void* d_ws, size_t ws_size,
                              hipStream_t stream) {
    const float* candidate = (const float*)d_in[2];
    const float* rcnn      = (const float*)d_in[3];
    const float* offset    = (const float*)d_in[4];
    const float* y         = (const float*)d_in[6];

    const int B = in_sizes[8];                 // horizon is [B]
    const int N = in_sizes[3] / (B * 2);       // RCNN is [B,N,2]
    const int h = in_sizes[6] / (B * 2);       // y is [B*h,2]

    float* out_f     = (float*)d_out;
    float* loss_slot = out_f + (size_t)B * N * 2;   // last element of d_out
    float* partials  = (float*)d_ws;

    const int n4   = (B * N * 2) / 4;          // 4,194,304 float4s
    const int row4 = N / 2;                    // 32,768 float4s per sample row
    const int chunk = 256 * 4;                 // 1024 float4s, divides row4
    const int nblk  = (n4 + chunk - 1) / chunk;   // 4096, exact

    fused_ntsteer_kernel<<<nblk, 256, 0, stream>>>(
        (const v4f*)candidate, (const v4f*)offset, (const v4f*)rcnn,
        (v4f*)d_out, partials, n4, nblk);

    const size_t shmem = (size_t)(B * h * 2 + 2 * B) * sizeof(float);
    final_reduce_gt_kernel<<<1, 256, shmem, stream>>>(
        partials, y, loss_slot, nblk, B, h, row4, chunk);
}

// Round 7
// 244.609 us; speedup vs baseline: 1.0951x; 1.0615x over previous
//
#include <hip/hip_runtime.h>

// Problem: B=128, N=65536, h=30.
// loss = sum_b sum_i ||gt[b] - (cand[b,i]+off[b,i])||^2  (argsort is a full
// permutation summed over afterwards -> irrelevant). RCNN passthrough.
// Output: RCNN_cls_result flat (B*N*2 floats) ++ loss (1 float).
//
// R1 lesson: same-address atomics serialize -> block partials (NOT one slot).
// R2 lesson: bounds-checked per-iter loop -> 1.9 TB/s.
// R3 lesson: __builtin_nontemporal_store needs a clang ext_vector type.
// R4 lesson: sched_barrier(0) can't stop IR-level load sinking.
// R5 lesson: stale-binary bench; wave-level concurrency was never the limiter.
// R6 lesson (split): pure 2-stream read 2.66 TB/s eff; fused ~3.0-3.2.
// R7 lesson (rolled 2048-blk): regression; R1 geometry (4096 blk, unrolled
//   U=4, upfront loads) is the measured optimum.
// R8 lesson (R1 geom + algebraic): 83.5 us, 2.0 TB/s — same wall everywhere.
// R9 lesson (nt-load rcnn): 71.5 us (+17%) with FETCH bit-identical ->
//   L3-residency theory FALSIFIED (nt does not change L3 allocation on
//   gfx950 loads); win is CACHE-PIPELINE CHURN: nt removes L1/L2
//   allocation/eviction work for that stream, raising service rate for all
//   streams. Hit-rate counters can't see it; duration does.
// R10 (this round): single variable — nt-load cand+off too. R9 proved nt
//   loads don't disturb the cross-iteration L3 hits, so there is no
//   hit-rate cost. Predict FETCH ~98.3 MB flat, main 71.5 -> 63-67 us.
//   If flat within 2%: churn lever exhausted -> declare roofline next.

typedef float v4f __attribute__((ext_vector_type(4)));

// Each block owns a contiguous chunk of 1024 float4s lying inside ONE sample
// row (1024 divides row4=32768), so (s2,s1x,s1y) bind to a single b.
__global__ __launch_bounds__(256) void fused_allnt_kernel(
    const v4f* __restrict__ cand, const v4f* __restrict__ off,
    const v4f* __restrict__ rcnn, v4f* __restrict__ out,
    float* __restrict__ partials,   // [3 * nblk] SoA: s2 | s1x | s1y
    int n4, int nblk)
{
    constexpr int U = 4;
    const size_t base = (size_t)blockIdx.x * (256 * U);

    float s2 = 0.f, s1x = 0.f, s1y = 0.f;
    if (base + 256 * U <= (size_t)n4) {      // uniform fast path (exact grid)
        // Issue all loads before any consumer (R1's measured-best pattern).
        // ALL streams nontemporal: no L1/L2 allocation churn anywhere.
        v4f c[U], o[U], r[U];
        #pragma unroll
        for (int u = 0; u < U; ++u)
            c[u] = __builtin_nontemporal_load(&cand[base + u * 256 + threadIdx.x]);
        #pragma unroll
        for (int u = 0; u < U; ++u)
            o[u] = __builtin_nontemporal_load(&off[base + u * 256 + threadIdx.x]);
        #pragma unroll
        for (int u = 0; u < U; ++u)
            r[u] = __builtin_nontemporal_load(&rcnn[base + u * 256 + threadIdx.x]);

        #pragma unroll
        for (int u = 0; u < U; ++u) {
            __builtin_nontemporal_store(r[u], &out[base + u * 256 + threadIdx.x]);
            float px0 = c[u].x + o[u].x, py0 = c[u].y + o[u].y;
            float px1 = c[u].z + o[u].z, py1 = c[u].w + o[u].w;
            s2  += px0 * px0; s2 += py0 * py0;
            s2  += px1 * px1; s2 += py1 * py1;
            s1x += px0 + px1;
            s1y += py0 + py1;
        }
    } else {                                  // tail (not taken for B=128,N=64K)
        #pragma unroll
        for (int u = 0; u < U; ++u) {
            size_t idx = base + u * 256 + threadIdx.x;
            if (idx < (size_t)n4) {
                v4f c = __builtin_nontemporal_load(&cand[idx]);
                v4f o = __builtin_nontemporal_load(&off[idx]);
                v4f r = __builtin_nontemporal_load(&rcnn[idx]);
                __builtin_nontemporal_store(r, &out[idx]);
                float px0 = c.x + o.x, py0 = c.y + o.y;
                float px1 = c.z + o.z, py1 = c.w + o.w;
                s2  += px0 * px0; s2 += py0 * py0;
                s2  += px1 * px1; s2 += py1 * py1;
                s1x += px0 + px1;
                s1y += py0 + py1;
            }
        }
    }

    #pragma unroll
    for (int s = 32; s > 0; s >>= 1) {
        s2  += __shfl_down(s2,  s, 64);
        s1x += __shfl_down(s1x, s, 64);
        s1y += __shfl_down(s1y, s, 64);
    }
    __shared__ float lds[12];
    int lane = threadIdx.x & 63, wid = threadIdx.x >> 6;
    if (lane == 0) { lds[wid] = s2; lds[4 + wid] = s1x; lds[8 + wid] = s1y; }
    __syncthreads();
    if (threadIdx.x == 0) {
        partials[blockIdx.x]            = lds[0] + lds[1] + lds[2]  + lds[3];
        partials[nblk + blockIdx.x]     = lds[4] + lds[5] + lds[6]  + lds[7];
        partials[2 * nblk + blockIdx.x] = lds[8] + lds[9] + lds[10] + lds[11];
    }
}

// ------------------------------------------------------------- final reduce
__global__ __launch_bounds__(256) void final_reduce_gt_kernel(
    const float* __restrict__ partials, const float* __restrict__ y,
    float* __restrict__ loss_slot,
    int nblk, int B, int h, int row4, int chunk)
{
    extern __shared__ float dyn[];          // [B*h*2] y staging ++ [2*B] gt
    float* yld = dyn;
    float* gt  = dyn + B * h * 2;

    const int ytot = B * h * 2;
    for (int i = threadIdx.x; i < ytot; i += 256) yld[i] = y[i];
    __syncthreads();

    for (int b = threadIdx.x; b < B; b += 256) {
        float gx = 0.f, gy = 0.f;
        const float* yr = yld + (size_t)b * h * 2;
        for (int i = 0; i < h; ++i) { gx += yr[2 * i]; gy += yr[2 * i + 1]; }
        gt[2 * b] = gx; gt[2 * b + 1] = gy;
    }
    __syncthreads();

    const int blocks_per_b = row4 / chunk;
    const float cnt_b = (float)(row4 * 2);   // points per sample = N
    float acc = 0.f;
    for (int k = threadIdx.x; k < nblk; k += 256) {
        int b = k / blocks_per_b;
        float gx = gt[2 * b], gy = gt[2 * b + 1];
        acc += partials[k]
             - 2.f * (gx * partials[nblk + k] + gy * partials[2 * nblk + k]);
    }
    for (int b = threadIdx.x; b < B; b += 256) {
        float gx = gt[2 * b], gy = gt[2 * b + 1];
        acc += cnt_b * (gx * gx + gy * gy);
    }

    #pragma unroll
    for (int s = 32; s > 0; s >>= 1) acc += __shfl_down(acc, s, 64);
    __shared__ float red[4];
    int lane = threadIdx.x & 63, wid = threadIdx.x >> 6;
    if (lane == 0) red[wid] = acc;
    __syncthreads();
    if (threadIdx.x == 0)
        *loss_slot = red[0] + red[1] + red[2] + red[3];
}

extern "C" void kernel_launch(void* const* d_in, const int* in_sizes, int n_in,
                              void* d_out, int out_size, void* d_ws, size_t ws_size,
                              hipStream_t stream) {
    const float* candidate = (const float*)d_in[2];
    const float* rcnn      = (const float*)d_in[3];
    const float* offset    = (const float*)d_in[4];
    const float* y         = (const float*)d_in[6];

    const int B = in_sizes[8];                 // horizon is [B]
    const int N = in_sizes[3] / (B * 2);       // RCNN is [B,N,2]
    const int h = in_sizes[6] / (B * 2);       // y is [B*h,2]

    float* out_f     = (float*)d_out;
    float* loss_slot = out_f + (size_t)B * N * 2;   // last element of d_out
    float* partials  = (float*)d_ws;

    const int n4   = (B * N * 2) / 4;          // 4,194,304 float4s
    const int row4 = N / 2;                    // 32,768 float4s per sample row
    const int chunk = 256 * 4;                 // 1024 float4s, divides row4
    const int nblk  = (n4 + chunk - 1) / chunk;   // 4096, exact

    fused_allnt_kernel<<<nblk, 256, 0, stream>>>(
        (const v4f*)candidate, (const v4f*)offset, (const v4f*)rcnn,
        (v4f*)d_out, partials, n4, nblk);

    const size_t shmem = (size_t)(B * h * 2 + 2 * B) * sizeof(float);
    final_reduce_gt_kernel<<<1, 256, shmem, stream>>>(
        partials, y, loss_slot, nblk, B, h, row4, chunk);
}